// Round 4
// baseline (680.404 us; speedup 1.0000x reference)
//
#include <hip/hip_runtime.h>
#include <hip/hip_bf16.h>
#include <cstdint>

#define SDIM 200
#define HDIM 128
#define IDIM 4
#define BDIM 1024
#define LDK 72      // bf16 staging leading dim for 64-wide K-half (144 B rows)
#define LDEF 132    // fp32 epilogue / routing-tile leading dim (528 B rows, 16B-aligned)

typedef __attribute__((ext_vector_type(8))) short short8;
typedef __attribute__((ext_vector_type(4))) float f32x4;

__device__ __forceinline__ ushort f32_to_bf16u(float f) {
    uint32_t u = __builtin_bit_cast(uint32_t, f);
    u += 0x7FFFu + ((u >> 16) & 1u);   // RNE
    return (ushort)(u >> 16);
}
__device__ __forceinline__ float bf16u_to_f32(ushort h) {
    uint32_t u = ((uint32_t)h) << 16;
    return __builtin_bit_cast(float, u);
}

// split 8 fp32 into hi/lo bf16 octets (16 B each)
__device__ __forceinline__ void split8(const float* p, uint4* hi, uint4* lo) {
    union { ushort u[8]; uint4 v; } xh, xl;
    #pragma unroll
    for (int j = 0; j < 8; ++j) {
        float f = p[j];
        ushort h = f32_to_bf16u(f);
        float r = f - bf16u_to_f32(h);
        xh.u[j] = h;
        xl.u[j] = f32_to_bf16u(r);
    }
    *hi = xh.v; *lo = xl.v;
}

// ---------------------------------------------------------------------------
// Kernel 1: hat[bl,i,s,h'] = sum_h item[b0+bl,s,h] * w[s, i*128+h', h]
// fp32 in -> split bf16 (hi+lo) -> 3-stream MFMA -> fp32 hat.
// One block per (s, i, 128-b-tile). K=128 staged in two 64-halves.
// LDS: 4 x 128 x 72 ushort = 73,728 B (epilogue overlays as fp32 [128][132]).
// ---------------------------------------------------------------------------
__global__ __launch_bounds__(256) void hat_gemm(const float* __restrict__ item,
                                                const float* __restrict__ w,
                                                float* __restrict__ hat,
                                                int b0, int nbt) {
    __shared__ ushort lds[4 * 128 * LDK];
    ushort* Ah = lds;
    ushort* Al = lds + 128 * LDK;
    ushort* Wh = lds + 2 * 128 * LDK;
    ushort* Wl = lds + 3 * 128 * LDK;
    float*  ef = (float*)lds;            // epilogue overlay [128][LDEF]

    const int blk = blockIdx.x;
    const int s  = blk / (IDIM * nbt);
    const int r  = blk % (IDIM * nbt);
    const int ii = r / nbt;
    const int bt = r % nbt;
    const int t  = threadIdx.x;

    const float* itemBase = item + ((size_t)(b0 + bt * 128) * SDIM + s) * HDIM;
    const float* wBase    = w + ((size_t)s * (IDIM * HDIM) + (size_t)ii * HDIM) * HDIM;

    const int wave = t >> 6, lane = t & 63;
    const int wm = wave >> 1, wn = wave & 1;   // 2x2 waves, each 64x64
    const int m0 = lane & 15, q = lane >> 4;

    f32x4 acc[4][4];
    #pragma unroll
    for (int tm = 0; tm < 4; ++tm)
        #pragma unroll
        for (int tn = 0; tn < 4; ++tn)
            acc[tm][tn] = (f32x4){0.f, 0.f, 0.f, 0.f};

    #pragma unroll
    for (int st = 0; st < 2; ++st) {
        const int kbase = st * 64;
        if (st) __syncthreads();
        // stage 128x64 halves of A and W: 1024 chunks of 8 fp32 each
        #pragma unroll
        for (int c = t; c < 1024; c += 256) {
            int row = c >> 3, g = c & 7;
            uint4 hi, lo;
            split8(itemBase + (size_t)row * (SDIM * HDIM) + kbase + g * 8, &hi, &lo);
            *(uint4*)(&Ah[row * LDK + g * 8]) = hi;
            *(uint4*)(&Al[row * LDK + g * 8]) = lo;
            split8(wBase + (size_t)row * HDIM + kbase + g * 8, &hi, &lo);
            *(uint4*)(&Wh[row * LDK + g * 8]) = hi;
            *(uint4*)(&Wl[row * LDK + g * 8]) = lo;
        }
        __syncthreads();

        #pragma unroll
        for (int kk = 0; kk < 2; ++kk) {
            const int kof = kk * 32 + q * 8;
            short8 ah[4], al[4], bh[4], bl[4];
            #pragma unroll
            for (int tm = 0; tm < 4; ++tm) {
                int ro = (wm * 64 + tm * 16 + m0) * LDK + kof;
                ah[tm] = *(const short8*)(&Ah[ro]);
                al[tm] = *(const short8*)(&Al[ro]);
            }
            #pragma unroll
            for (int tn = 0; tn < 4; ++tn) {
                int ro = (wn * 64 + tn * 16 + m0) * LDK + kof;
                bh[tn] = *(const short8*)(&Wh[ro]);
                bl[tn] = *(const short8*)(&Wl[ro]);
            }
            #pragma unroll
            for (int tm = 0; tm < 4; ++tm)
                #pragma unroll
                for (int tn = 0; tn < 4; ++tn) {
                    acc[tm][tn] = __builtin_amdgcn_mfma_f32_16x16x32_bf16(
                        ah[tm], bl[tn], acc[tm][tn], 0, 0, 0);
                    acc[tm][tn] = __builtin_amdgcn_mfma_f32_16x16x32_bf16(
                        al[tm], bh[tn], acc[tm][tn], 0, 0, 0);
                    acc[tm][tn] = __builtin_amdgcn_mfma_f32_16x16x32_bf16(
                        ah[tm], bh[tn], acc[tm][tn], 0, 0, 0);
                }
        }
    }
    __syncthreads();

    // epilogue: acc (fp32) -> LDS overlay [128][LDEF], then 16B global stores
    #pragma unroll
    for (int tm = 0; tm < 4; ++tm) {
        #pragma unroll
        for (int tn = 0; tn < 4; ++tn) {
            int col = wn * 64 + tn * 16 + m0;
            #pragma unroll
            for (int rg = 0; rg < 4; ++rg) {
                int row = wm * 64 + tm * 16 + q * 4 + rg;
                ef[row * LDEF + col] = acc[tm][tn][rg];
            }
        }
    }
    __syncthreads();
    #pragma unroll
    for (int c = t; c < 4096; c += 256) {
        int row = c >> 5, cc = c & 31;
        int bl_ = bt * 128 + row;   // chunk-local b
        float4 v = *(const float4*)(&ef[row * LDEF + cc * 4]);
        *(float4*)(hat + (((size_t)bl_ * IDIM + ii) * SDIM + s) * HDIM + cc * 4) = v;
    }
}

// ---------------------------------------------------------------------------
// Kernel 2: full dynamic routing for one (b, i), all fp32.
// LDS: hs 105,600 + aux ~11 KB = ~117 KB (gfx950 allows up to 160 KB/wg).
// ---------------------------------------------------------------------------
__global__ __launch_bounds__(256) void routing(const float* __restrict__ hat,
                                               const int* __restrict__ mask,
                                               float* __restrict__ out,
                                               int b0) {
    __shared__ float hs[SDIM * LDEF];      // 105,600 B
    __shared__ float cw[SDIM];
    __shared__ float sw[SDIM];
    __shared__ float icp[16 * HDIM];       // stripe partials
    __shared__ float ic[HDIM];
    __shared__ int   mk[SDIM];
    __shared__ float scal;
    __shared__ float scal2;

    const int blk = blockIdx.x;
    const int bl = blk >> 2, ii = blk & 3;
    const int b = b0 + bl;
    const int t = threadIdx.x;
    const float* hbase = hat + ((size_t)bl * IDIM + ii) * (SDIM * HDIM);

    // load hat tile: 200x128 fp32 = 6400 float4 chunks
    for (int c = t; c < 6400; c += 256) {
        int row = c >> 5, cc = c & 31;
        float4 v = *(const float4*)(hbase + (size_t)row * HDIM + cc * 4);
        *(float4*)(&hs[row * LDEF + cc * 4]) = v;
    }
    if (t < SDIM) { mk[t] = mask[b * SDIM + t]; cw[t] = 0.0f; }
    __syncthreads();

    for (int iter = 0; iter < 3; ++iter) {
        // softmax over all 200 entries, then zero masked (NOT renormalized)
        if (t < 64) {
            float m = -1e30f;
            for (int sj = t; sj < SDIM; sj += 64) m = fmaxf(m, cw[sj]);
            #pragma unroll
            for (int off = 32; off > 0; off >>= 1) m = fmaxf(m, __shfl_down(m, off));
            if (t == 0) scal = m;
        }
        __syncthreads();
        if (t < SDIM) sw[t] = expf(cw[t] - scal);
        __syncthreads();
        if (t < 64) {
            float d = 0.f;
            for (int sj = t; sj < SDIM; sj += 64) d += sw[sj];
            #pragma unroll
            for (int off = 32; off > 0; off >>= 1) d += __shfl_down(d, off);
            if (t == 0) scal2 = d;
        }
        __syncthreads();
        if (t < SDIM) sw[t] = mk[t] ? sw[t] / scal2 : 0.0f;
        __syncthreads();

        // ic[h] = sum_s sw[s] * hat[s,h]   (16 s-stripes x 16 h-octets)
        {
            const int hq = (t & 15) * 8;
            const int stripe = t >> 4;
            float a[8] = {0, 0, 0, 0, 0, 0, 0, 0};
            for (int sj = stripe; sj < SDIM; sj += 16) {
                float wgt = sw[sj];
                const float* p = &hs[sj * LDEF + hq];
                float4 v0 = *(const float4*)(p);
                float4 v1 = *(const float4*)(p + 4);
                a[0] = fmaf(wgt, v0.x, a[0]); a[1] = fmaf(wgt, v0.y, a[1]);
                a[2] = fmaf(wgt, v0.z, a[2]); a[3] = fmaf(wgt, v0.w, a[3]);
                a[4] = fmaf(wgt, v1.x, a[4]); a[5] = fmaf(wgt, v1.y, a[5]);
                a[6] = fmaf(wgt, v1.z, a[6]); a[7] = fmaf(wgt, v1.w, a[7]);
            }
            #pragma unroll
            for (int j = 0; j < 8; ++j) icp[stripe * HDIM + hq + j] = a[j];
        }
        __syncthreads();
        if (t < HDIM) {
            float val = 0.0f;
            #pragma unroll
            for (int st = 0; st < 16; ++st) val += icp[st * HDIM + t];
            ic[t] = val;
        }
        __syncthreads();

        // squash: n = sum ic^2; f = n/(1+n)/sqrt(n+eps)
        if (t < 64) {
            float p = ic[t] * ic[t] + ic[t + 64] * ic[t + 64];
            #pragma unroll
            for (int off = 32; off > 0; off >>= 1) p += __shfl_down(p, off);
            if (t == 0) scal = p;
        }
        __syncthreads();
        {
            float n = scal;
            float factor = n / (1.0f + n) / sqrtf(n + 1e-9f);
            if (t < HDIM) ic[t] = ic[t] * factor;
        }
        __syncthreads();

        // delta[s] = <hat[s,:], ic>; cw += delta  (iters 0,1)
        if (iter < 2) {
            if (t < SDIM) {
                float d = 0.0f;
                #pragma unroll
                for (int c = 0; c < 32; ++c) {
                    float4 v = *(const float4*)(&hs[t * LDEF + c * 4]);
                    d = fmaf(v.x, ic[c * 4 + 0], d);
                    d = fmaf(v.y, ic[c * 4 + 1], d);
                    d = fmaf(v.z, ic[c * 4 + 2], d);
                    d = fmaf(v.w, ic[c * 4 + 3], d);
                }
                cw[t] += d;
            }
            __syncthreads();
        }
    }

    if (t < HDIM)
        out[((size_t)b * IDIM + ii) * HDIM + t] = ic[t];
}

extern "C" void kernel_launch(void* const* d_in, const int* in_sizes, int n_in,
                              void* d_out, int out_size, void* d_ws, size_t ws_size,
                              hipStream_t stream) {
    // resolve inputs by element count (distinct sizes) to be order-robust
    const float* item = nullptr;   // 1024*200*128 = 26,214,400
    const int*   msk  = nullptr;   // 1024*200    =    204,800
    const float* w    = nullptr;   // 200*512*128 = 13,107,200
    for (int i = 0; i < n_in; ++i) {
        if (in_sizes[i] == BDIM * SDIM * HDIM)            item = (const float*)d_in[i];
        else if (in_sizes[i] == BDIM * SDIM)              msk  = (const int*)d_in[i];
        else if (in_sizes[i] == SDIM * IDIM * HDIM * HDIM) w   = (const float*)d_in[i];
    }
    if (!item) item = (const float*)d_in[0];
    if (!msk)  msk  = (const int*)d_in[1];
    if (!w)    w    = (const float*)d_in[2];

    float* hat = (float*)d_ws;                 // chunk of (B,I,S,H) fp32
    float* out = (float*)d_out;                // (B,I,H) fp32

    const size_t perB = (size_t)IDIM * SDIM * HDIM * sizeof(float);  // 409,600 B
    int chunk = BDIM;                                                 // 419.4 MB full
    if (ws_size < perB * (size_t)BDIM) {
        chunk = (int)(ws_size / perB);
        chunk = (chunk / 128) * 128;       // GEMM b-tile granularity
        if (chunk < 128) chunk = 128;      // last resort
    }
    for (int bb = 0; bb < BDIM; bb += chunk) {
        int cb = (BDIM - bb < chunk) ? (BDIM - bb) : chunk;
        int nbt = cb / 128;
        hat_gemm<<<SDIM * IDIM * nbt, 256, 0, stream>>>(item, w, hat, bb, nbt);
        routing<<<cb * IDIM, 256, 0, stream>>>(hat, msk, out, bb);
    }
}